// Round 3
// baseline (162.724 us; speedup 1.0000x reference)
//
#include <hip/hip_runtime.h>

#define NN 8192
#define FIN 256
#define FOUT 128
#define BKJ 128            /* j per step */
#define NEGB -9.0e15f
#define LALPHA 0.2f
#define RTH 7.0f

typedef short bf16x8 __attribute__((ext_vector_type(8)));
typedef float f32x4 __attribute__((ext_vector_type(4)));

static __device__ __forceinline__ unsigned short f2bf(float f) {
    unsigned u = __float_as_uint(f);
    u += 0x7FFFu + ((u >> 16) & 1u);   // RNE
    return (unsigned short)(u >> 16);
}
static __device__ __forceinline__ float bf2f(unsigned short b) {
    return __uint_as_float(((unsigned)b) << 16);
}

// ---------------- K1: Wh = h@W (f32), si = Wh@a1, sj = Wh@a2, WhT bf16 ----------------
// grid 256 blocks x 256 thr; block = 32 rows. Thread: 4 rows x 4 cols register tile.
__global__ __launch_bounds__(256) void gat_k1(
    const float* __restrict__ h, const float* __restrict__ W,
    const float* __restrict__ a, unsigned short* __restrict__ WhT,
    float* __restrict__ si, float* __restrict__ sj)
{
    __shared__ float Wt[64 * 128];          // 32 KB: W chunk [64k][128c]
    __shared__ float hT[64 * 36 + 4];       // 9 KB: h chunk transposed [64k][32r] pad 36
    const int t = threadIdx.x;
    const int r0 = blockIdx.x * 32;
    const int rg = t >> 5;    // 0..7 -> rows rg*4..+4
    const int cg = t & 31;    // 0..31 -> cols cg*4..+4
    float acc[4][4] = {{0.f,0.f,0.f,0.f},{0.f,0.f,0.f,0.f},{0.f,0.f,0.f,0.f},{0.f,0.f,0.f,0.f}};

    for (int kc = 0; kc < 4; ++kc) {
        __syncthreads();
        const float4* Ws = (const float4*)(W + kc * 64 * FOUT);
        float4* Wd = (float4*)Wt;
        #pragma unroll
        for (int v = 0; v < 8; ++v) Wd[v * 256 + t] = Ws[v * 256 + t];
        {
            const int hr = t >> 3, hk = (t & 7) * 8;
            const float* hs = h + (size_t)(r0 + hr) * FIN + kc * 64 + hk;
            float4 x0 = *(const float4*)hs;
            float4 x1 = *(const float4*)(hs + 4);
            hT[(hk + 0) * 36 + hr] = x0.x; hT[(hk + 1) * 36 + hr] = x0.y;
            hT[(hk + 2) * 36 + hr] = x0.z; hT[(hk + 3) * 36 + hr] = x0.w;
            hT[(hk + 4) * 36 + hr] = x1.x; hT[(hk + 5) * 36 + hr] = x1.y;
            hT[(hk + 6) * 36 + hr] = x1.z; hT[(hk + 7) * 36 + hr] = x1.w;
        }
        __syncthreads();
        #pragma unroll 8
        for (int kk = 0; kk < 64; ++kk) {
            float4 hv4 = *(const float4*)&hT[kk * 36 + rg * 4];
            float4 wv4 = *(const float4*)&Wt[kk * 128 + cg * 4];
            float hv[4] = {hv4.x, hv4.y, hv4.z, hv4.w};
            float wv[4] = {wv4.x, wv4.y, wv4.z, wv4.w};
            #pragma unroll
            for (int rr = 0; rr < 4; ++rr)
                #pragma unroll
                for (int cc = 0; cc < 4; ++cc)
                    acc[rr][cc] = fmaf(hv[rr], wv[cc], acc[rr][cc]);
        }
    }
    float4 a1v4 = *(const float4*)(a + cg * 4);
    float4 a2v4 = *(const float4*)(a + FOUT + cg * 4);
    float a1v[4] = {a1v4.x, a1v4.y, a1v4.z, a1v4.w};
    float a2v[4] = {a2v4.x, a2v4.y, a2v4.z, a2v4.w};
    float ps[4], qs[4];
    #pragma unroll
    for (int rr = 0; rr < 4; ++rr) {
        float p = 0.f, q = 0.f;
        #pragma unroll
        for (int cc = 0; cc < 4; ++cc) {
            p = fmaf(acc[rr][cc], a1v[cc], p);
            q = fmaf(acc[rr][cc], a2v[cc], q);
        }
        ps[rr] = p; qs[rr] = q;
    }
    #pragma unroll
    for (int off = 1; off <= 16; off <<= 1) {
        #pragma unroll
        for (int rr = 0; rr < 4; ++rr) {
            ps[rr] += __shfl_xor(ps[rr], off);
            qs[rr] += __shfl_xor(qs[rr], off);
        }
    }
    if (cg == 0) {
        #pragma unroll
        for (int rr = 0; rr < 4; ++rr) {
            si[r0 + rg * 4 + rr] = ps[rr];
            sj[r0 + rg * 4 + rr] = qs[rr];
        }
    }
    #pragma unroll
    for (int cc = 0; cc < 4; ++cc) {
        ushort4 v;
        v.x = f2bf(acc[0][cc]); v.y = f2bf(acc[1][cc]);
        v.z = f2bf(acc[2][cc]); v.w = f2bf(acc[3][cc]);
        *(ushort4*)(WhT + (size_t)(cg * 4 + cc) * NN + r0 + rg * 4) = v;
    }
}

// ---------------- K2: flash-style masked softmax + P@Wh via MFMA ----------------
// JS=4: grid 512 = 128 row-blocks x 4 j-splits, partials to ml/Opart.
// JS=1 (FINAL): grid 128, full j-range per block, normalize+ELU+write out directly.
template<int JS, bool FINAL>
__global__ __launch_bounds__(256, 2) void gat_k2(
    const int* __restrict__ adj, const unsigned short* __restrict__ WhT,
    const float* __restrict__ si, const float* __restrict__ sj,
    float2* __restrict__ ml, float* __restrict__ Opart, float* __restrict__ out)
{
    const int JR_ = NN / JS;
    const int NST_ = JR_ / BKJ;
    __shared__ __align__(16) unsigned short tile[2][16384];   // 2 x 32 KB WhT tile [128c][128j]
    const int t = threadIdx.x;
    const int w = t >> 6, l = t & 63;
    const int rb = (int)blockIdx.x / JS, js = (int)blockIdx.x % JS;
    const int iw = rb * 64 + w * 16;       // wave's 16 rows
    const int j0 = js * JR_;
    const int row = l & 15, kg = l >> 4;   // A-frag: row=l&15, k-slice=kg*8..+8

    const float si_l = si[iw + row];
    const float* sjb = sj + j0 + kg * 8;

    const int c_row = t >> 4;
    const int ch = t & 15;
    const unsigned short* gsrc[8];
    int ldsoff[8];
    #pragma unroll
    for (int v = 0; v < 8; ++v) {
        int c = v * 16 + c_row;
        gsrc[v] = WhT + (size_t)c * NN + j0 + ch * 8;
        ldsoff[v] = ((v * 256 + t) * 16) ^ ((c_row & 7) << 4);
    }
    const int* adjb = adj + (size_t)(iw + row) * NN + j0 + kg * 8;

    int4 stg[8], adr[8];
    #pragma unroll
    for (int v = 0; v < 8; ++v) stg[v] = *(const int4*)(gsrc[v]);
    #pragma unroll
    for (int q = 0; q < 8; ++q) adr[q] = *(const int4*)(adjb + (q >> 1) * 32 + (q & 1) * 4);

    f32x4 acc[8];
    #pragma unroll
    for (int n = 0; n < 8; ++n) { acc[n][0] = 0.f; acc[n][1] = 0.f; acc[n][2] = 0.f; acc[n][3] = 0.f; }
    float m_run = -INFINITY, ls = 0.f;

    #pragma unroll 2
    for (int s = 0; s < NST_; ++s) {
        const int cur = s & 1;
        unsigned short* tb = tile[cur];
        #pragma unroll
        for (int v = 0; v < 8; ++v)
            *(int4*)((char*)tb + ldsoff[v]) = stg[v];
        if (s + 1 < NST_) {
            #pragma unroll
            for (int v = 0; v < 8; ++v) stg[v] = *(const int4*)(gsrc[v] + (size_t)(s + 1) * BKJ);
        }
        float e[32];
        float pmax = -INFINITY;
        #pragma unroll
        for (int kc = 0; kc < 4; ++kc) {
            float4 s0 = *(const float4*)(sjb + s * BKJ + kc * 32);
            float4 s1 = *(const float4*)(sjb + s * BKJ + kc * 32 + 4);
            const int4 A0 = adr[kc * 2], A1 = adr[kc * 2 + 1];
            float sv[8] = {s0.x, s0.y, s0.z, s0.w, s1.x, s1.y, s1.z, s1.w};
            int av[8] = {A0.x, A0.y, A0.z, A0.w, A1.x, A1.y, A1.z, A1.w};
            #pragma unroll
            for (int m = 0; m < 8; ++m) {
                float x = si_l + sv[m];
                x = fmaxf(x, LALPHA * x);               // leaky_relu, alpha<1
                float ev = (av[m] > 0) ? x : NEGB;
                e[kc * 8 + m] = ev;
                pmax = fmaxf(pmax, ev);
            }
        }
        if (s + 1 < NST_) {
            #pragma unroll
            for (int q = 0; q < 8; ++q)
                adr[q] = *(const int4*)(adjb + (size_t)(s + 1) * BKJ + (q >> 1) * 32 + (q & 1) * 4);
        }
        pmax = fmaxf(pmax, __shfl_xor(pmax, 16));
        pmax = fmaxf(pmax, __shfl_xor(pmax, 32));
        if (__any(pmax > m_run + RTH)) {
            float mnew = fmaxf(m_run, pmax);
            float sc = __expf(m_run - mnew);
            ls *= sc;
            float c0 = __shfl(sc, kg * 4 + 0);
            float c1 = __shfl(sc, kg * 4 + 1);
            float c2 = __shfl(sc, kg * 4 + 2);
            float c3 = __shfl(sc, kg * 4 + 3);
            #pragma unroll
            for (int n = 0; n < 8; ++n) {
                acc[n][0] *= c0; acc[n][1] *= c1; acc[n][2] *= c2; acc[n][3] *= c3;
            }
            m_run = mnew;
        }
        bf16x8 af[4];
        #pragma unroll
        for (int kc = 0; kc < 4; ++kc) {
            #pragma unroll
            for (int m = 0; m < 8; ++m) {
                float p = __expf(e[kc * 8 + m] - m_run);
                unsigned short pb = f2bf(p);
                ls += bf2f(pb);
                af[kc][m] = (short)pb;
            }
        }
        __syncthreads();   // tile[cur] fully written; prior-step reads done
        #pragma unroll
        for (int kc = 0; kc < 4; ++kc) {
            #pragma unroll
            for (int n = 0; n < 8; ++n) {
                const int c = n * 16 + row;
                const int off = c * 256 + (((kc * 32 + kg * 8) * 2) ^ ((c & 7) << 4));
                bf16x8 bf = *(const bf16x8*)((const char*)tb + off);
                acc[n] = __builtin_amdgcn_mfma_f32_16x16x32_bf16(af[kc], bf, acc[n], 0, 0, 0);
            }
        }
    }
    ls += __shfl_xor(ls, 16);
    ls += __shfl_xor(ls, 32);
    if (FINAL) {
        // single split: m cancels between num and den; o = acc/ls, then ELU
        #pragma unroll
        for (int r = 0; r < 4; ++r) {
            float lsr = __shfl(ls, kg * 4 + r);   // lane (kg*4+r) holds row (kg*4+r)'s sum
            #pragma unroll
            for (int n = 0; n < 8; ++n) {
                float o = acc[n][r] / lsr;
                o = (o > 0.f) ? o : expm1f(o);
                out[(size_t)(iw + kg * 4 + r) * FOUT + n * 16 + row] = o;
            }
        }
    } else {
        if (l < 16) ml[(size_t)js * NN + iw + l] = make_float2(m_run, ls);
        #pragma unroll
        for (int n = 0; n < 8; ++n)
            #pragma unroll
            for (int r = 0; r < 4; ++r)
                Opart[((size_t)js * NN + iw + kg * 4 + r) * FOUT + n * 16 + row] = acc[n][r];
    }
}

// ---------------- K3: merge j-splits (LSE combine), divide, ELU ----------------
__global__ __launch_bounds__(256) void gat_k3(
    const float2* __restrict__ ml, const float* __restrict__ Opart,
    float* __restrict__ out)
{
    const int t = threadIdx.x;
    const int i = (int)blockIdx.x * 2 + (t >> 7);
    const int f = t & 127;
    float2 v0 = ml[i];
    float2 v1 = ml[NN + i];
    float2 v2 = ml[2 * NN + i];
    float2 v3 = ml[3 * NN + i];
    float M = fmaxf(fmaxf(v0.x, v1.x), fmaxf(v2.x, v3.x));
    float w0 = __expf(v0.x - M), w1 = __expf(v1.x - M);
    float w2 = __expf(v2.x - M), w3 = __expf(v3.x - M);
    float den = w0 * v0.y + w1 * v1.y + w2 * v2.y + w3 * v3.y;
    size_t base = (size_t)i * FOUT + f;
    const size_t SP = (size_t)NN * FOUT;
    float num = w0 * Opart[base] + w1 * Opart[SP + base]
              + w2 * Opart[2 * SP + base] + w3 * Opart[3 * SP + base];
    float o = num / den;
    out[base] = (o > 0.f) ? o : expm1f(o);   // ELU, alpha=1
}

extern "C" void kernel_launch(void* const* d_in, const int* in_sizes, int n_in,
                              void* d_out, int out_size, void* d_ws, size_t ws_size,
                              hipStream_t stream) {
    const float* h  = (const float*)d_in[0];
    const int*  adj = (const int*)d_in[1];
    const float* W  = (const float*)d_in[2];
    const float* a  = (const float*)d_in[3];
    float* out = (float*)d_out;
    char* ws = (char*)d_ws;
    // ws layout: WhT bf16 2MB | si 32KB | sj 32KB | ml 256KB | Opart 16MB  (~19.2 MB)
    unsigned short* WhT = (unsigned short*)ws;
    float*  si    = (float*)(ws + 2097152);
    float*  sj    = (float*)(ws + 2097152 + 32768);
    float2* ml    = (float2*)(ws + 2097152 + 65536);
    float*  Opart = (float*)(ws + 2097152 + 65536 + 262144);
    const size_t need4 = 2097152 + 65536 + 262144 + (size_t)4 * NN * FOUT * 4;

    gat_k1<<<256, 256, 0, stream>>>(h, W, a, WhT, si, sj);
    if (ws_size >= need4) {
        gat_k2<4, false><<<512, 256, 0, stream>>>(adj, WhT, si, sj, ml, Opart, out);
        gat_k3<<<4096, 256, 0, stream>>>(ml, Opart, out);
    } else {
        gat_k2<1, true><<<128, 256, 0, stream>>>(adj, WhT, si, sj, ml, Opart, out);
    }
}

// Round 4
// 98.579 us; speedup vs baseline: 1.6507x; 1.6507x over previous
//
#include <hip/hip_runtime.h>

#define NN 8192
#define FIN 256
#define FOUT 128
#define BKJ 128            /* j per step */
#define LALPHA 0.2f

typedef short bf16x8 __attribute__((ext_vector_type(8)));
typedef float f32x4 __attribute__((ext_vector_type(4)));

#define FOR8(X) X(0) X(1) X(2) X(3) X(4) X(5) X(6) X(7)

static __device__ __forceinline__ unsigned short f2bf(float f) {
    unsigned u = __float_as_uint(f);
    u += 0x7FFFu + ((u >> 16) & 1u);   // RNE
    return (unsigned short)(u >> 16);
}
static __device__ __forceinline__ float bf2f(unsigned short b) {
    return __uint_as_float(((unsigned)b) << 16);
}

// ---------------- K1: Wh = h@W (f32), si = Wh@a1, sj = Wh@a2, WhT bf16 ----------------
__global__ __launch_bounds__(256) void gat_k1(
    const float* __restrict__ h, const float* __restrict__ W,
    const float* __restrict__ a, unsigned short* __restrict__ WhT,
    float* __restrict__ si, float* __restrict__ sj)
{
    __shared__ float Wt[64 * 128];          // 32 KB: W chunk [64k][128c]
    __shared__ float hT[64 * 36 + 4];       // 9 KB: h chunk transposed [64k][32r] pad 36
    const int t = threadIdx.x;
    const int r0 = blockIdx.x * 32;
    const int rg = t >> 5;    // rows rg*4..+4
    const int cg = t & 31;    // cols cg*4..+4
    float acc[4][4] = {{0.f,0.f,0.f,0.f},{0.f,0.f,0.f,0.f},{0.f,0.f,0.f,0.f},{0.f,0.f,0.f,0.f}};

    for (int kc = 0; kc < 4; ++kc) {
        __syncthreads();
        const float4* Ws = (const float4*)(W + kc * 64 * FOUT);
        float4* Wd = (float4*)Wt;
        #pragma unroll
        for (int v = 0; v < 8; ++v) Wd[v * 256 + t] = Ws[v * 256 + t];
        {
            const int hr = t >> 3, hk = (t & 7) * 8;
            const float* hs = h + (size_t)(r0 + hr) * FIN + kc * 64 + hk;
            float4 x0 = *(const float4*)hs;
            float4 x1 = *(const float4*)(hs + 4);
            hT[(hk + 0) * 36 + hr] = x0.x; hT[(hk + 1) * 36 + hr] = x0.y;
            hT[(hk + 2) * 36 + hr] = x0.z; hT[(hk + 3) * 36 + hr] = x0.w;
            hT[(hk + 4) * 36 + hr] = x1.x; hT[(hk + 5) * 36 + hr] = x1.y;
            hT[(hk + 6) * 36 + hr] = x1.z; hT[(hk + 7) * 36 + hr] = x1.w;
        }
        __syncthreads();
        #pragma unroll 8
        for (int kk = 0; kk < 64; ++kk) {
            float4 hv4 = *(const float4*)&hT[kk * 36 + rg * 4];
            float4 wv4 = *(const float4*)&Wt[kk * 128 + cg * 4];
            float hv[4] = {hv4.x, hv4.y, hv4.z, hv4.w};
            float wv[4] = {wv4.x, wv4.y, wv4.z, wv4.w};
            #pragma unroll
            for (int rr = 0; rr < 4; ++rr)
                #pragma unroll
                for (int cc = 0; cc < 4; ++cc)
                    acc[rr][cc] = fmaf(hv[rr], wv[cc], acc[rr][cc]);
        }
    }
    float4 a1v4 = *(const float4*)(a + cg * 4);
    float4 a2v4 = *(const float4*)(a + FOUT + cg * 4);
    float a1v[4] = {a1v4.x, a1v4.y, a1v4.z, a1v4.w};
    float a2v[4] = {a2v4.x, a2v4.y, a2v4.z, a2v4.w};
    float ps[4], qs[4];
    #pragma unroll
    for (int rr = 0; rr < 4; ++rr) {
        float p = 0.f, q = 0.f;
        #pragma unroll
        for (int cc = 0; cc < 4; ++cc) {
            p = fmaf(acc[rr][cc], a1v[cc], p);
            q = fmaf(acc[rr][cc], a2v[cc], q);
        }
        ps[rr] = p; qs[rr] = q;
    }
    #pragma unroll
    for (int off = 1; off <= 16; off <<= 1) {
        #pragma unroll
        for (int rr = 0; rr < 4; ++rr) {
            ps[rr] += __shfl_xor(ps[rr], off);
            qs[rr] += __shfl_xor(qs[rr], off);
        }
    }
    if (cg == 0) {
        #pragma unroll
        for (int rr = 0; rr < 4; ++rr) {
            si[r0 + rg * 4 + rr] = ps[rr];
            sj[r0 + rg * 4 + rr] = qs[rr];
        }
    }
    #pragma unroll
    for (int cc = 0; cc < 4; ++cc) {
        ushort4 v;
        v.x = f2bf(acc[0][cc]); v.y = f2bf(acc[1][cc]);
        v.z = f2bf(acc[2][cc]); v.w = f2bf(acc[3][cc]);
        *(ushort4*)(WhT + (size_t)(cg * 4 + cc) * NN + r0 + rg * 4) = v;
    }
}

// ---------------- K1s: sjmax = max_j sj[j] (global, one scalar) ----------------
__global__ __launch_bounds__(256) void gat_k1s(
    const float* __restrict__ sj, float* __restrict__ sjmax)
{
    __shared__ float red[256];
    float m = -1e30f;
    for (int i = threadIdx.x; i < NN; i += 256) m = fmaxf(m, sj[i]);
    red[threadIdx.x] = m;
    __syncthreads();
    for (int o = 128; o > 0; o >>= 1) {
        if (threadIdx.x < o) red[threadIdx.x] = fmaxf(red[threadIdx.x], red[threadIdx.x + o]);
        __syncthreads();
    }
    if (threadIdx.x == 0) sjmax[0] = red[0];
}

// ---------------- K2: fixed-m masked softmax + P@Wh via MFMA ----------------
static __device__ __forceinline__ unsigned short pcalc(
    int a, float sjv, float si_l, float m_row, float& ls)
{
    float x = si_l + sjv;
    x = fmaxf(x, LALPHA * x);                 // leaky_relu
    float p = (a > 0) ? __expf(x - m_row) : 0.f;   // x <= m_row guaranteed
    unsigned short pb = f2bf(p);
    ls += bf2f(pb);                           // denominator matches bf16-rounded numerator
    return pb;
}

template<int JS, bool FINAL>
__global__ __launch_bounds__(256, 2) void gat_k2(
    const int* __restrict__ adj, const unsigned short* __restrict__ WhT,
    const float* __restrict__ si, const float* __restrict__ sj,
    const float* __restrict__ sjmaxp,
    float* __restrict__ lsum, float* __restrict__ Opart, float* __restrict__ out)
{
    const int JR_ = NN / JS;
    const int NST_ = JR_ / BKJ;
    __shared__ __align__(16) unsigned short tile[2][16384];   // 2 x 32 KB WhT tile [128c][128j], XOR-swizzled
    const int t = threadIdx.x;
    const int w = t >> 6, l = t & 63;
    const int rb = (int)blockIdx.x / JS, js = (int)blockIdx.x % JS;
    const int iw = rb * 64 + w * 16;       // wave's 16 rows
    const int j0 = js * JR_;
    const int row = l & 15, kg = l >> 4;   // MFMA A-frag: row = l&15, k-slice = kg*8..+8

    const float si_l = si[iw + row];
    const float sjmax = sjmaxp[0];
    const float xm = si_l + sjmax;
    const float m_row = fmaxf(xm, LALPHA * xm);   // upper bound on every masked score of this row
    const float* sjb = sj + j0 + kg * 8;
    const int c_row = t >> 4, ch = t & 15;
    const int* adjb = adj + (size_t)(iw + row) * NN + j0 + kg * 8;

    // staging: lane t handles WhT column c=v*16+c_row, 16B chunk ch; LDS byte = linear^((c&7)<<4)
#define GSRC_D(v) const unsigned short* gsrc##v = WhT + (size_t)(v * 16 + c_row) * NN + j0 + ch * 8; \
                  const int ldo##v = ((v * 256 + t) * 16) ^ ((c_row & 7) << 4);
    FOR8(GSRC_D)

#define REG_D(v) int4 stg##v, adr##v;
    FOR8(REG_D)

    // prologue: stage step 0
#define STG_L0(v) stg##v = *(const int4*)(gsrc##v);
    FOR8(STG_L0)
#define ADR_L0(q) adr##q = *(const int4*)(adjb + (q / 2) * 32 + (q % 2) * 4);
    FOR8(ADR_L0)

#define ACC_D(n) f32x4 acc##n = {0.f, 0.f, 0.f, 0.f};
    FOR8(ACC_D)
    float ls = 0.f;
    const int kg16 = kg * 16;

#define STG_WR(v) *(int4*)((char*)tb + ldo##v) = stg##v;
#define STG_LN(v) stg##v = *(const int4*)(gsrc##v + so);
#define ADR_LN(q) adr##q = *(const int4*)(adjb + so + (q / 2) * 32 + (q % 2) * 4);
#define P8(AF, A0, A1, sp) { \
    float4 s0_ = *(const float4*)(sp); float4 s1_ = *(const float4*)((sp) + 4); \
    AF[0] = (short)pcalc(A0.x, s0_.x, si_l, m_row, ls); \
    AF[1] = (short)pcalc(A0.y, s0_.y, si_l, m_row, ls); \
    AF[2] = (short)pcalc(A0.z, s0_.z, si_l, m_row, ls); \
    AF[3] = (short)pcalc(A0.w, s0_.w, si_l, m_row, ls); \
    AF[4] = (short)pcalc(A1.x, s1_.x, si_l, m_row, ls); \
    AF[5] = (short)pcalc(A1.y, s1_.y, si_l, m_row, ls); \
    AF[6] = (short)pcalc(A1.z, s1_.z, si_l, m_row, ls); \
    AF[7] = (short)pcalc(A1.w, s1_.w, si_l, m_row, ls); }
#define MFMA_ROW(n) { const int c_ = n * 16 + row; \
    const int off_ = c_ * 256 + (KB ^ ((c_ & 7) << 4)); \
    bf16x8 bv_ = *(const bf16x8*)((const char*)tb + off_); \
    acc##n = __builtin_amdgcn_mfma_f32_16x16x32_bf16(AFk, bv_, acc##n, 0, 0, 0); }
#define MFMA_KC(afv, kcl) { const bf16x8 AFk = afv; const int KB = kcl * 64 + kg16; FOR8(MFMA_ROW) }

    for (int s = 0; s < NST_; ++s) {
        unsigned short* tb = tile[s & 1];
        // A: write staged WhT tile (swizzled b128 writes)
        FOR8(STG_WR)
        // B: issue next stage loads (regs now free)
        if (s + 1 < NST_) {
            const size_t so = (size_t)(s + 1) * BKJ;
            FOR8(STG_LN)
        }
        // C: scores -> p (bf16) inline, accumulate ls
        bf16x8 af0, af1, af2, af3;
        {
            const float* spp = sjb + s * BKJ;
            P8(af0, adr0, adr1, spp)
            P8(af1, adr2, adr3, spp + 32)
            P8(af2, adr4, adr5, spp + 64)
            P8(af3, adr6, adr7, spp + 96)
        }
        // D: issue next adj loads
        if (s + 1 < NST_) {
            const size_t so = (size_t)(s + 1) * BKJ;
            FOR8(ADR_LN)
        }
        __syncthreads();   // tile[cur] written by all waves; prior reads done
        // F: MFMA 4 k-chunks x 8 col-tiles
        MFMA_KC(af0, 0) MFMA_KC(af1, 1) MFMA_KC(af2, 2) MFMA_KC(af3, 3)
    }

    ls += __shfl_xor(ls, 16);
    ls += __shfl_xor(ls, 32);
    if (FINAL) {
        float lsr0 = __shfl(ls, kg * 4 + 0);
        float lsr1 = __shfl(ls, kg * 4 + 1);
        float lsr2 = __shfl(ls, kg * 4 + 2);
        float lsr3 = __shfl(ls, kg * 4 + 3);
#define FN_ROW(n) { size_t ob = (size_t)(iw + kg * 4) * FOUT + n * 16 + row; \
    float o0 = acc##n[0] / lsr0; out[ob]            = (o0 > 0.f) ? o0 : expm1f(o0); \
    float o1 = acc##n[1] / lsr1; out[ob + FOUT]     = (o1 > 0.f) ? o1 : expm1f(o1); \
    float o2 = acc##n[2] / lsr2; out[ob + 2 * FOUT] = (o2 > 0.f) ? o2 : expm1f(o2); \
    float o3 = acc##n[3] / lsr3; out[ob + 3 * FOUT] = (o3 > 0.f) ? o3 : expm1f(o3); }
        FOR8(FN_ROW)
    } else {
        if (l < 16) lsum[(size_t)js * NN + iw + l] = ls;
#define ST_ROW(n) { size_t ob = ((size_t)js * NN + iw + kg * 4) * FOUT + n * 16 + row; \
    Opart[ob] = acc##n[0]; Opart[ob + FOUT] = acc##n[1]; \
    Opart[ob + 2 * FOUT] = acc##n[2]; Opart[ob + 3 * FOUT] = acc##n[3]; }
        FOR8(ST_ROW)
    }
}

// ---------------- K3: merge j-splits (plain sums; shared fixed m), divide, ELU ----------------
__global__ __launch_bounds__(256) void gat_k3(
    const float* __restrict__ lsum, const float* __restrict__ Opart,
    float* __restrict__ out)
{
    const int t = threadIdx.x;
    const int i = (int)blockIdx.x * 2 + (t >> 7);
    const int f = t & 127;
    float den = lsum[i] + lsum[NN + i] + lsum[2 * NN + i] + lsum[3 * NN + i];
    size_t base = (size_t)i * FOUT + f;
    const size_t SP = (size_t)NN * FOUT;
    float num = Opart[base] + Opart[SP + base]
              + Opart[2 * SP + base] + Opart[3 * SP + base];
    float o = num / den;
    out[base] = (o > 0.f) ? o : expm1f(o);   // ELU, alpha=1
}

extern "C" void kernel_launch(void* const* d_in, const int* in_sizes, int n_in,
                              void* d_out, int out_size, void* d_ws, size_t ws_size,
                              hipStream_t stream) {
    const float* h  = (const float*)d_in[0];
    const int*  adj = (const int*)d_in[1];
    const float* W  = (const float*)d_in[2];
    const float* a  = (const float*)d_in[3];
    float* out = (float*)d_out;
    char* ws = (char*)d_ws;
    // ws: WhT 2MB | si 32KB | sj 32KB | sjmax 256B | lsum 128KB | Opart 16MB
    unsigned short* WhT = (unsigned short*)ws;
    float* si     = (float*)(ws + 2097152);
    float* sj     = (float*)(ws + 2129920);
    float* sjmax  = (float*)(ws + 2162688);
    float* lsum   = (float*)(ws + 2162944);
    float* Opart  = (float*)(ws + 2294016);
    const size_t need4 = 2294016 + (size_t)4 * NN * FOUT * 4;   // ~19.1 MB

    gat_k1<<<256, 256, 0, stream>>>(h, W, a, WhT, si, sj);
    gat_k1s<<<1, 256, 0, stream>>>(sj, sjmax);
    if (ws_size >= need4) {
        gat_k2<4, false><<<512, 256, 0, stream>>>(adj, WhT, si, sj, sjmax, lsum, Opart, out);
        gat_k3<<<4096, 256, 0, stream>>>(lsum, Opart, out);
    } else {
        gat_k2<1, true><<<128, 256, 0, stream>>>(adj, WhT, si, sj, sjmax, lsum, Opart, out);
    }
}